// Round 2
// baseline (8995.783 us; speedup 1.0000x reference)
//
#include <hip/hip_runtime.h>
#include <stdint.h>

#define BATCH 32
#define SEQ   128       // S == T == 128
#define HID   512
#define VTOK  32000

typedef unsigned short u16;
typedef unsigned int   u32;
typedef float    f32x4  __attribute__((ext_vector_type(4)));
typedef short    short8 __attribute__((ext_vector_type(8)));
typedef _Float16 half2t __attribute__((ext_vector_type(2)));

__device__ __forceinline__ u16 f2bf(float f) {
    u32 u = __builtin_bit_cast(u32, f);
    return (u16)((u + 0x7FFFu + ((u >> 16) & 1u)) >> 16);
}
__device__ __forceinline__ u16 f2h_bits(float f) {
    return __builtin_bit_cast(u16, (_Float16)f);
}
__device__ __forceinline__ float dot2f16(u32 a, u32 b, float c) {
#if __has_builtin(__builtin_amdgcn_fdot2)
    return __builtin_amdgcn_fdot2(__builtin_bit_cast(half2t, a),
                                  __builtin_bit_cast(half2t, b), c, false);
#else
    half2t av = __builtin_bit_cast(half2t, a), bv = __builtin_bit_cast(half2t, b);
    return c + (float)av.x * (float)bv.x + (float)av.y * (float)bv.y;
#endif
}
__device__ __forceinline__ void dot4x(float& acc, uint4 wv, uint4 hv) {
    acc = dot2f16(wv.x, hv.x, acc); acc = dot2f16(wv.y, hv.y, acc);
    acc = dot2f16(wv.z, hv.z, acc); acc = dot2f16(wv.w, hv.w, acc);
}

__device__ __forceinline__ float fexp2(float x) { return __builtin_amdgcn_exp2f(x); }
__device__ __forceinline__ float frcp(float x)  { return __builtin_amdgcn_rcpf(x); }
__device__ __forceinline__ float sigmoid_f(float x) {
    return frcp(1.f + fexp2(-1.442695040888963f * x));
}
__device__ __forceinline__ float tanh_f(float x) {
    // tanh(x) = 1 - 2/(1+e^{2x});  e^{2x} = 2^(2*log2(e)*x)
    return 1.f - 2.f * frcp(1.f + fexp2(2.885390081777927f * x));
}

// ---------------- prep kernels ----------------

// f32 [K,N] -> bf16 [N,K]
__global__ __launch_bounds__(256) void transpose_cvt(
    const float* __restrict__ src, u16* __restrict__ dst, int K, int N)
{
    __shared__ float tile[32][33];
    const int n0 = blockIdx.x * 32, k0 = blockIdx.y * 32;
    const int tx = threadIdx.x & 31, ty = threadIdx.x >> 5;
    #pragma unroll
    for (int j = 0; j < 32; j += 8)
        tile[ty + j][tx] = src[(size_t)(k0 + ty + j) * N + n0 + tx];
    __syncthreads();
    #pragma unroll
    for (int j = 0; j < 32; j += 8)
        dst[(size_t)(n0 + ty + j) * K + k0 + tx] = f2bf(tile[tx][ty + j]);
}

// f32 [K,N] -> f16 pack [K/8][N][8]
__global__ __launch_bounds__(256) void pack8_f16(
    const float* __restrict__ src, _Float16* __restrict__ dst, int N)
{
    const int n  = blockIdx.x * 256 + threadIdx.x;
    const int kb = blockIdx.y;
    __align__(16) _Float16 v[8];
    #pragma unroll
    for (int j = 0; j < 8; ++j)
        v[j] = (_Float16)src[(size_t)(kb * 8 + j) * N + n];
    *(uint4*)(dst + ((size_t)kb * N + n) * 8) = *(const uint4*)v;
}

// embedding gather -> bf16 rows [4096, 512]
__global__ __launch_bounds__(128) void gather_emb_bf16(
    const int* __restrict__ idx, const float* __restrict__ emb, u16* __restrict__ out)
{
    const int r = blockIdx.x;
    const int token = idx[r];
    const int i = threadIdx.x * 4;
    float4 v = *(const float4*)(emb + (size_t)token * 512 + i);
    uint2 pk;
    pk.x = (u32)f2bf(v.x) | ((u32)f2bf(v.y) << 16);
    pk.y = (u32)f2bf(v.z) | ((u32)f2bf(v.w) << 16);
    *(uint2*)(out + (size_t)r * 512 + i) = pk;
}

// ---------------- MFMA GEMM:  C[M,N](f32) = A[M,K](bf16) * BT[N,K](bf16) + bias ----------------
__global__ __launch_bounds__(256) void gemm_bf16(
    const u16* __restrict__ A, const u16* __restrict__ BT,
    const float* __restrict__ bias, float* __restrict__ C,
    int M, int N, int K)
{
    __shared__ __align__(16) u16 As[128][40];
    __shared__ __align__(16) u16 Bs[128][40];
    const int tid  = threadIdx.x;
    const int lane = tid & 63, wave = tid >> 6;
    const int wm = (wave & 1) * 64, wn = (wave >> 1) * 64;
    const int lrow = lane & 15, lk = (lane >> 4) * 8;
    const int srow = tid >> 2, skof = (tid & 3) * 8;
    const size_t K_ = (size_t)K;
    const u16* Ag = A + ((size_t)blockIdx.y * 128 + srow) * K_ + skof;
    const u16* Bg = BT + ((size_t)blockIdx.x * 128 + srow) * K_ + skof;
    f32x4 acc[4][4] = {};
    for (int k0 = 0; k0 < K; k0 += 32) {
        uint4 a0 = *(const uint4*)(Ag + k0);
        uint4 a1 = *(const uint4*)(Ag + 64 * K_ + k0);
        uint4 b0 = *(const uint4*)(Bg + k0);
        uint4 b1 = *(const uint4*)(Bg + 64 * K_ + k0);
        __syncthreads();
        *(uint4*)&As[srow][skof]      = a0;
        *(uint4*)&As[srow + 64][skof] = a1;
        *(uint4*)&Bs[srow][skof]      = b0;
        *(uint4*)&Bs[srow + 64][skof] = b1;
        __syncthreads();
        short8 af[4], bf[4];
        #pragma unroll
        for (int i = 0; i < 4; ++i) af[i] = *(const short8*)&As[wm + i * 16 + lrow][lk];
        #pragma unroll
        for (int j = 0; j < 4; ++j) bf[j] = *(const short8*)&Bs[wn + j * 16 + lrow][lk];
        #pragma unroll
        for (int i = 0; i < 4; ++i)
            #pragma unroll
            for (int j = 0; j < 4; ++j)
                acc[i][j] = __builtin_amdgcn_mfma_f32_16x16x32_bf16(af[i], bf[j], acc[i][j], 0, 0, 0);
    }
    const int crow0 = blockIdx.y * 128 + wm + (lane >> 4) * 4;
    const int ccol0 = blockIdx.x * 128 + wn + (lane & 15);
    #pragma unroll
    for (int j = 0; j < 4; ++j) {
        const float bv = bias ? bias[ccol0 + j * 16] : 0.f;
        #pragma unroll
        for (int i = 0; i < 4; ++i)
            #pragma unroll
            for (int rr = 0; rr < 4; ++rr)
                C[(size_t)(crow0 + i * 16 + rr) * N + (ccol0 + j * 16)] = acc[i][j][rr] + bv;
    }
}

// ---------------- encoder recurrence: one workgroup per batch element ----------------
__global__ __launch_bounds__(512) void encoder_rec(
    const float* __restrict__ gx,        // [B*S,1536]  x@Wx + bx
    const _Float16* __restrict__ pUrz,   // [64][1024][8]
    const _Float16* __restrict__ pUn,    // [64][512][8]
    const float* __restrict__ brz, const float* __restrict__ bn,
    u16* __restrict__ enc_hs_bf,         // [B*S,512] bf16
    _Float16* __restrict__ spack,        // [B][16][512][8]
    float* __restrict__ h0dec, u32* __restrict__ h0p)
{
    const int b = blockIdx.x, tid = threadIdx.x;
    __shared__ __align__(16) u32 hp[256];
    __shared__ __align__(16) u32 rhp[256];
    __shared__ float hf[512];
    if (tid < 256) hp[tid] = 0u;
    hf[tid] = 0.f;
    __syncthreads();
    for (int t = 0; t < SEQ; ++t) {
        const float* gxr = gx + (size_t)(b * SEQ + t) * 1536;
        float a0 = 0.f, a1 = 0.f;
        #pragma unroll 4
        for (int kb = 0; kb < 64; ++kb) {
            uint4 hv = *(const uint4*)&hp[kb * 4];
            uint4 w0 = *(const uint4*)(pUrz + ((size_t)kb * 1024 + tid) * 8);
            uint4 w1 = *(const uint4*)(pUrz + ((size_t)kb * 1024 + 512 + tid) * 8);
            dot4x(a0, w0, hv); dot4x(a1, w1, hv);
        }
        const float hold = hf[tid];
        const float r = sigmoid_f(gxr[tid] + a0 + brz[tid]);
        const float z = sigmoid_f(gxr[512 + tid] + a1 + brz[512 + tid]);
        ((u16*)rhp)[tid] = f2h_bits(r * hold);
        __syncthreads();
        float an = 0.f;
        #pragma unroll 4
        for (int kb = 0; kb < 64; ++kb) {
            uint4 hv = *(const uint4*)&rhp[kb * 4];
            uint4 wn_ = *(const uint4*)(pUn + ((size_t)kb * 512 + tid) * 8);
            dot4x(an, wn_, hv);
        }
        const float n = tanh_f(gxr[1024 + tid] + an + bn[tid]);
        const float hnew = (1.f - z) * hold + z * n;
        hf[tid] = hnew;
        ((u16*)hp)[tid] = f2h_bits(hnew);
        enc_hs_bf[(size_t)(b * SEQ + t) * 512 + tid] = f2bf(hnew);
        spack[(((size_t)b * 16 + (t >> 3)) * 512 + tid) * 8 + (t & 7)] = (_Float16)hnew;
        __syncthreads();
    }
    h0dec[b * 512 + tid] = hf[tid];
    if (tid < 256) h0p[b * 256 + tid] = hp[tid];
}

// ---------------- decoder recurrence: one workgroup per batch element ----------------
__global__ __launch_bounds__(512) void decoder_rec(
    const float* __restrict__ gxe,       // [B*T,1536]  emb@WxE + bx
    const float* __restrict__ wh_enc,    // [B*S,512] f32
    const _Float16* __restrict__ spack,  // [B][16][512][8]
    const _Float16* __restrict__ pWs,    // [64][512][8]
    const _Float16* __restrict__ pWxC,   // [64][1536][8]
    const _Float16* __restrict__ pUrz,   // [64][1024][8]
    const _Float16* __restrict__ pUn,    // [64][512][8]
    const float* __restrict__ attn_v,    // [512]
    const float* __restrict__ brz, const float* __restrict__ bn,
    const float* __restrict__ h0, const u32* __restrict__ h0pair,
    u16* __restrict__ hctx)              // [B*T,1024] bf16: [h | ctx]
{
    const int b = blockIdx.x, tid = threadIdx.x;
    __shared__ __align__(16) u32 hp[256], rhp[256], ctxp[256], attnp[64];
    __shared__ __align__(16) float hf[512], hWs[512], red[512];
    hf[tid] = h0[b * 512 + tid];
    if (tid < 256) hp[tid] = h0pair[b * 256 + tid];
    __syncthreads();
    for (int t = 0; t < SEQ; ++t) {
        const float* gxr = gxe + (size_t)(b * SEQ + t) * 1536;
        // P1: hrz (regs a0,a1) + hWs (LDS)
        float a0 = 0.f, a1 = 0.f, aw = 0.f;
        #pragma unroll 4
        for (int kb = 0; kb < 64; ++kb) {
            uint4 hv = *(const uint4*)&hp[kb * 4];
            uint4 w0 = *(const uint4*)(pUrz + ((size_t)kb * 1024 + tid) * 8);
            uint4 w1 = *(const uint4*)(pUrz + ((size_t)kb * 1024 + 512 + tid) * 8);
            uint4 ww = *(const uint4*)(pWs + ((size_t)kb * 512 + tid) * 8);
            dot4x(a0, w0, hv); dot4x(a1, w1, hv); dot4x(aw, ww, hv);
        }
        hWs[tid] = aw;
        __syncthreads();
        // P2: energy partials; thread -> (s = tid>>2, quarter g = tid&3)
        {
            const int s = tid >> 2, g = tid & 3;
            const float* whr = wh_enc + (size_t)(b * SEQ + s) * 512 + g * 128;
            const float* vv  = attn_v + g * 128;
            const float* hwp = &hWs[g * 128];
            float e = 0.f;
            #pragma unroll 4
            for (int i = 0; i < 128; i += 4) {
                float4 w4  = *(const float4*)(whr + i);
                float4 hw = *(const float4*)(hwp + i);
                float4 v4 = *(const float4*)(vv + i);
                e += v4.x * tanh_f(w4.x + hw.x) + v4.y * tanh_f(w4.y + hw.y)
                   + v4.z * tanh_f(w4.z + hw.z) + v4.w * tanh_f(w4.w + hw.w);
            }
            red[tid] = e;
        }
        __syncthreads();
        // softmax over S=128 by wave 0 (s=tid and s=tid+64)
        if (tid < 64) {
            float e0 = red[4 * tid] + red[4 * tid + 1] + red[4 * tid + 2] + red[4 * tid + 3];
            float e1 = red[4 * (tid + 64)] + red[4 * (tid + 64) + 1]
                     + red[4 * (tid + 64) + 2] + red[4 * (tid + 64) + 3];
            float m = fmaxf(e0, e1);
            for (int o = 32; o >= 1; o >>= 1) m = fmaxf(m, __shfl_xor(m, o));
            float p0 = fexp2((e0 - m) * 1.442695040888963f);
            float p1 = fexp2((e1 - m) * 1.442695040888963f);
            float ss = p0 + p1;
            for (int o = 32; o >= 1; o >>= 1) ss += __shfl_xor(ss, o);
            const float inv = frcp(ss);
            ((u16*)attnp)[tid]      = f2h_bits(p0 * inv);
            ((u16*)attnp)[tid + 64] = f2h_bits(p1 * inv);
        }
        __syncthreads();
        // ctx[i] = sum_s attn[s] * enc_hs[b,s,i]  (s-packed f16, dot2)
        {
            float c = 0.f;
            const _Float16* sp = spack + (((size_t)b * 16) * 512 + tid) * 8;
            #pragma unroll 4
            for (int sb = 0; sb < 16; ++sb) {
                uint4 sv = *(const uint4*)(sp + (size_t)sb * 512 * 8);
                uint4 ap = *(const uint4*)&attnp[sb * 4];
                dot4x(c, sv, ap);
            }
            ((u16*)ctxp)[tid] = f2h_bits(c);
            hctx[(size_t)(b * SEQ + t) * 1024 + 512 + tid] = f2bf(c);
        }
        __syncthreads();
        // P3a: gxc = ctx @ WxC (3 cols/thread)
        float g0 = 0.f, g1 = 0.f, g2 = 0.f;
        #pragma unroll 4
        for (int kb = 0; kb < 64; ++kb) {
            uint4 cv = *(const uint4*)&ctxp[kb * 4];
            uint4 w0 = *(const uint4*)(pWxC + ((size_t)kb * 1536 + tid) * 8);
            uint4 w1 = *(const uint4*)(pWxC + ((size_t)kb * 1536 + 512 + tid) * 8);
            uint4 w2 = *(const uint4*)(pWxC + ((size_t)kb * 1536 + 1024 + tid) * 8);
            dot4x(g0, w0, cv); dot4x(g1, w1, cv); dot4x(g2, w2, cv);
        }
        const float hold = hf[tid];
        const float r = sigmoid_f(gxr[tid] + g0 + a0 + brz[tid]);
        const float z = sigmoid_f(gxr[512 + tid] + g1 + a1 + brz[512 + tid]);
        ((u16*)rhp)[tid] = f2h_bits(r * hold);
        __syncthreads();
        // P3b: un = (r*h) @ Un
        float un = 0.f;
        #pragma unroll 4
        for (int kb = 0; kb < 64; ++kb) {
            uint4 hv = *(const uint4*)&rhp[kb * 4];
            uint4 wn_ = *(const uint4*)(pUn + ((size_t)kb * 512 + tid) * 8);
            dot4x(un, wn_, hv);
        }
        const float n = tanh_f(gxr[1024 + tid] + g2 + un + bn[tid]);
        const float hnew = (1.f - z) * hold + z * n;
        hf[tid] = hnew;
        ((u16*)hp)[tid] = f2h_bits(hnew);
        hctx[(size_t)(b * SEQ + t) * 1024 + tid] = f2bf(hnew);
        __syncthreads();
    }
}

// ---------------- log_softmax per row, in-place on [4096, 32000] ----------------
__global__ __launch_bounds__(256) void log_softmax_rows(float* __restrict__ out)
{
    const int row = blockIdx.x, tid = threadIdx.x;
    float* p = out + (size_t)row * VTOK;
    __shared__ float rb[4];
    float m = -3.0e38f;
    for (int i = tid * 4; i < VTOK; i += 1024) {
        float4 v = *(const float4*)(p + i);
        m = fmaxf(m, fmaxf(fmaxf(v.x, v.y), fmaxf(v.z, v.w)));
    }
    for (int o = 32; o >= 1; o >>= 1) m = fmaxf(m, __shfl_xor(m, o));
    if ((tid & 63) == 0) rb[tid >> 6] = m;
    __syncthreads();
    m = fmaxf(fmaxf(rb[0], rb[1]), fmaxf(rb[2], rb[3]));
    float s = 0.f;
    for (int i = tid * 4; i < VTOK; i += 1024) {
        float4 v = *(const float4*)(p + i);
        s += fexp2((v.x - m) * 1.442695040888963f) + fexp2((v.y - m) * 1.442695040888963f)
           + fexp2((v.z - m) * 1.442695040888963f) + fexp2((v.w - m) * 1.442695040888963f);
    }
    for (int o = 32; o >= 1; o >>= 1) s += __shfl_xor(s, o);
    __syncthreads();
    if ((tid & 63) == 0) rb[tid >> 6] = s;
    __syncthreads();
    s = rb[0] + rb[1] + rb[2] + rb[3];
    const float lse = m + __builtin_amdgcn_logf(s) * 0.6931471805599453f;
    for (int i = tid * 4; i < VTOK; i += 1024) {
        float4 v = *(const float4*)(p + i);
        v.x -= lse; v.y -= lse; v.z -= lse; v.w -= lse;
        *(float4*)(p + i) = v;
    }
}

// ---------------- host launcher ----------------
extern "C" void kernel_launch(void* const* d_in, const int* in_sizes, int n_in,
                              void* d_out, int out_size, void* d_ws, size_t ws_size,
                              hipStream_t stream)
{
    (void)in_sizes; (void)n_in; (void)out_size; (void)ws_size;
    const int*   src       = (const int*)  d_in[0];
    const int*   tgt       = (const int*)  d_in[1];
    const float* enc_embed = (const float*)d_in[2];
    const float* enc_Wx    = (const float*)d_in[3];
    const float* enc_bx    = (const float*)d_in[4];
    const float* enc_Urz   = (const float*)d_in[5];
    const float* enc_brz   = (const float*)d_in[6];
    const float* enc_Un    = (const float*)d_in[7];
    const float* enc_bn    = (const float*)d_in[8];
    const float* dec_embed = (const float*)d_in[9];
    const float* dec_Wx    = (const float*)d_in[10];
    const float* dec_bx    = (const float*)d_in[11];
    const float* dec_Urz   = (const float*)d_in[12];
    const float* dec_brz   = (const float*)d_in[13];
    const float* dec_Un    = (const float*)d_in[14];
    const float* dec_bn    = (const float*)d_in[15];
    const float* attn_Wh   = (const float*)d_in[16];
    const float* attn_Ws   = (const float*)d_in[17];
    const float* attn_v    = (const float*)d_in[18];
    const float* out_W     = (const float*)d_in[19];
    const float* out_b     = (const float*)d_in[20];

    // --- scratch carved out of d_out (524,288,000 B); all consumed before the final GEMM overwrites it ---
    char* ob = (char*)d_out;
    float*    gx_enc  = (float*)   (ob + 0);          // 4096*1536*4 = 25165824
    float*    gxe_dec = (float*)   (ob + 25165824);   // 25165824
    float*    wh_enc  = (float*)   (ob + 50331648);   // 4096*512*4 = 8388608
    u16*      Aenc    = (u16*)     (ob + 58720256);   // 4096*512*2 = 4194304
    u16*      Adec    = (u16*)     (ob + 62914560);   // 4194304
    u16*      enc_hs  = (u16*)     (ob + 67108864);   // 4194304
    _Float16* spack   = (_Float16*)(ob + 71303168);   // 4194304
    u16*      encWxT  = (u16*)     (ob + 75497472);   // 1536*512*2 = 1572864
    u16*      WhT     = (u16*)     (ob + 77070336);   // 512*512*2 = 524288
    u16*      decWxET = (u16*)     (ob + 77594624);   // 1572864
    _Float16* pEncUrz = (_Float16*)(ob + 79167488);   // 512*1024*2 = 1048576
    _Float16* pEncUn  = (_Float16*)(ob + 80216064);   // 524288
    _Float16* pDecUrz = (_Float16*)(ob + 80740352);   // 1048576
    _Float16* pDecUn  = (_Float16*)(ob + 81788928);   // 524288
    _Float16* pWs     = (_Float16*)(ob + 82313216);   // 524288
    _Float16* pWxC    = (_Float16*)(ob + 82837504);   // 512*1536*2 = 1572864
    float*    h0dec   = (float*)   (ob + 84410368);   // 65536
    u32*      h0p     = (u32*)     (ob + 84475904);   // 32768

    // --- d_ws: only what must coexist with the final GEMM's output ---
    char* wb = (char*)d_ws;
    u16* outWT = (u16*)(wb + 0);          // 32000*1024*2 = 65536000
    u16* hctx  = (u16*)(wb + 65536000);   // 4096*1024*2 = 8388608

    // prep: transposes (bf16 B^T for MFMA) + packs (f16 for dot2 GEMV)
    transpose_cvt<<<dim3(48, 16),   256, 0, stream>>>(enc_Wx,  encWxT, 512, 1536);
    transpose_cvt<<<dim3(16, 16),   256, 0, stream>>>(attn_Wh, WhT,    512, 512);
    transpose_cvt<<<dim3(48, 16),   256, 0, stream>>>(dec_Wx,  decWxET,512, 1536);
    transpose_cvt<<<dim3(1000, 32), 256, 0, stream>>>(out_W,   outWT, 1024, 32000);
    pack8_f16<<<dim3(4, 64), 256, 0, stream>>>(enc_Urz, pEncUrz, 1024);
    pack8_f16<<<dim3(2, 64), 256, 0, stream>>>(enc_Un,  pEncUn,  512);
    pack8_f16<<<dim3(4, 64), 256, 0, stream>>>(dec_Urz, pDecUrz, 1024);
    pack8_f16<<<dim3(2, 64), 256, 0, stream>>>(dec_Un,  pDecUn,  512);
    pack8_f16<<<dim3(2, 64), 256, 0, stream>>>(attn_Ws, pWs,     512);
    pack8_f16<<<dim3(6, 64), 256, 0, stream>>>(dec_Wx + (size_t)512 * 1536, pWxC, 1536);
    gather_emb_bf16<<<4096, 128, 0, stream>>>(src, enc_embed, Aenc);
    gather_emb_bf16<<<4096, 128, 0, stream>>>(tgt, dec_embed, Adec);

    // batched input-projection GEMMs
    gemm_bf16<<<dim3(12, 32), 256, 0, stream>>>(Aenc, encWxT,  enc_bx, gx_enc,  4096, 1536, 512);
    gemm_bf16<<<dim3(12, 32), 256, 0, stream>>>(Adec, decWxET, dec_bx, gxe_dec, 4096, 1536, 512);

    // encoder scan
    encoder_rec<<<32, 512, 0, stream>>>(gx_enc, pEncUrz, pEncUn, enc_brz, enc_bn,
                                        enc_hs, spack, h0dec, h0p);
    // wh_enc = enc_hs @ attn_Wh
    gemm_bf16<<<dim3(4, 32), 256, 0, stream>>>(enc_hs, WhT, nullptr, wh_enc, 4096, 512, 512);

    // decoder scan (attention + GRU), stores [h|ctx] bf16
    decoder_rec<<<32, 512, 0, stream>>>(gxe_dec, wh_enc, spack, pWs, pWxC, pDecUrz, pDecUn,
                                        attn_v, dec_brz, dec_bn, h0dec, h0p, hctx);

    // output projection: overwrites ALL of d_out (scratch above is fully consumed)
    gemm_bf16<<<dim3(250, 32), 256, 0, stream>>>(hctx, outWT, out_b, (float*)d_out, 4096, VTOK, 1024);

    // in-place log_softmax
    log_softmax_rows<<<4096, 256, 0, stream>>>((float*)d_out);
}

// Round 3
// 8706.657 us; speedup vs baseline: 1.0332x; 1.0332x over previous
//
#include <hip/hip_runtime.h>
#include <stdint.h>

#define BATCH 32
#define SEQ   128       // S == T == 128
#define HID   512
#define VTOK  32000

typedef unsigned short u16;
typedef unsigned int   u32;
typedef float    f32x4  __attribute__((ext_vector_type(4)));
typedef short    short8 __attribute__((ext_vector_type(8)));
typedef _Float16 half2t __attribute__((ext_vector_type(2)));

__device__ __forceinline__ u16 f2bf(float f) {
    u32 u = __builtin_bit_cast(u32, f);
    return (u16)((u + 0x7FFFu + ((u >> 16) & 1u)) >> 16);
}
__device__ __forceinline__ float bf2f(u16 v) {
    u32 u = ((u32)v) << 16; return __builtin_bit_cast(float, u);
}
__device__ __forceinline__ u16 f2h_bits(float f) {
    return __builtin_bit_cast(u16, (_Float16)f);
}
__device__ __forceinline__ float dot2f16(u32 a, u32 b, float c) {
#if __has_builtin(__builtin_amdgcn_fdot2)
    return __builtin_amdgcn_fdot2(__builtin_bit_cast(half2t, a),
                                  __builtin_bit_cast(half2t, b), c, false);
#else
    half2t av = __builtin_bit_cast(half2t, a), bv = __builtin_bit_cast(half2t, b);
    return c + (float)av.x * (float)bv.x + (float)av.y * (float)bv.y;
#endif
}
__device__ __forceinline__ void dot4x(float& acc, uint4 wv, uint4 hv) {
    acc = dot2f16(wv.x, hv.x, acc); acc = dot2f16(wv.y, hv.y, acc);
    acc = dot2f16(wv.z, hv.z, acc); acc = dot2f16(wv.w, hv.w, acc);
}

__device__ __forceinline__ float fexp2(float x) { return __builtin_amdgcn_exp2f(x); }
__device__ __forceinline__ float frcp(float x)  { return __builtin_amdgcn_rcpf(x); }
__device__ __forceinline__ float sigmoid_f(float x) {
    return frcp(1.f + fexp2(-1.442695040888963f * x));
}
__device__ __forceinline__ float tanh_f(float x) {
    return 1.f - 2.f * frcp(1.f + fexp2(2.885390081777927f * x));
}

// ---------------- prep kernels ----------------

// f32 [K,N] -> bf16 [N,K]
__global__ __launch_bounds__(256) void transpose_cvt(
    const float* __restrict__ src, u16* __restrict__ dst, int K, int N)
{
    __shared__ float tile[32][33];
    const int n0 = blockIdx.x * 32, k0 = blockIdx.y * 32;
    const int tx = threadIdx.x & 31, ty = threadIdx.x >> 5;
    #pragma unroll
    for (int j = 0; j < 32; j += 8)
        tile[ty + j][tx] = src[(size_t)(k0 + ty + j) * N + n0 + tx];
    __syncthreads();
    #pragma unroll
    for (int j = 0; j < 32; j += 8)
        dst[(size_t)(n0 + ty + j) * K + k0 + tx] = f2bf(tile[tx][ty + j]);
}

// f32 [K,N] -> f16 pack [K/8][N][8]
__global__ __launch_bounds__(256) void pack8_f16(
    const float* __restrict__ src, _Float16* __restrict__ dst, int N)
{
    const int n  = blockIdx.x * 256 + threadIdx.x;
    const int kb = blockIdx.y;
    __align__(16) _Float16 v[8];
    #pragma unroll
    for (int j = 0; j < 8; ++j)
        v[j] = (_Float16)src[(size_t)(kb * 8 + j) * N + n];
    *(uint4*)(dst + ((size_t)kb * N + n) * 8) = *(const uint4*)v;
}

// f32 -> bf16 (flat), 8 elems/thread
__global__ __launch_bounds__(256) void cvt_f32_bf16(
    const float* __restrict__ src, u16* __restrict__ dst)
{
    const size_t i = ((size_t)blockIdx.x * 256 + threadIdx.x) * 8;
    float4 v0 = *(const float4*)(src + i);
    float4 v1 = *(const float4*)(src + i + 4);
    uint4 pk;
    pk.x = (u32)f2bf(v0.x) | ((u32)f2bf(v0.y) << 16);
    pk.y = (u32)f2bf(v0.z) | ((u32)f2bf(v0.w) << 16);
    pk.z = (u32)f2bf(v1.x) | ((u32)f2bf(v1.y) << 16);
    pk.w = (u32)f2bf(v1.z) | ((u32)f2bf(v1.w) << 16);
    *(uint4*)(dst + i) = pk;
}

// embedding gather -> bf16 rows [4096, 512]
__global__ __launch_bounds__(128) void gather_emb_bf16(
    const int* __restrict__ idx, const float* __restrict__ emb, u16* __restrict__ out)
{
    const int r = blockIdx.x;
    const int token = idx[r];
    const int i = threadIdx.x * 4;
    float4 v = *(const float4*)(emb + (size_t)token * 512 + i);
    uint2 pk;
    pk.x = (u32)f2bf(v.x) | ((u32)f2bf(v.y) << 16);
    pk.y = (u32)f2bf(v.z) | ((u32)f2bf(v.w) << 16);
    *(uint2*)(out + (size_t)r * 512 + i) = pk;
}

// ---------------- MFMA GEMM:  C[M,N](f32) = A[M,K](bf16) * BT[N,K](bf16) + bias ----------------
__global__ __launch_bounds__(256) void gemm_bf16(
    const u16* __restrict__ A, const u16* __restrict__ BT,
    const float* __restrict__ bias, float* __restrict__ C,
    int M, int N, int K)
{
    __shared__ __align__(16) u16 As[128][40];
    __shared__ __align__(16) u16 Bs[128][40];
    const int tid  = threadIdx.x;
    const int lane = tid & 63, wave = tid >> 6;
    const int wm = (wave & 1) * 64, wn = (wave >> 1) * 64;
    const int lrow = lane & 15, lk = (lane >> 4) * 8;
    const int srow = tid >> 2, skof = (tid & 3) * 8;
    const size_t K_ = (size_t)K;
    const u16* Ag = A + ((size_t)blockIdx.y * 128 + srow) * K_ + skof;
    const u16* Bg = BT + ((size_t)blockIdx.x * 128 + srow) * K_ + skof;
    f32x4 acc[4][4] = {};
    for (int k0 = 0; k0 < K; k0 += 32) {
        uint4 a0 = *(const uint4*)(Ag + k0);
        uint4 a1 = *(const uint4*)(Ag + 64 * K_ + k0);
        uint4 b0 = *(const uint4*)(Bg + k0);
        uint4 b1 = *(const uint4*)(Bg + 64 * K_ + k0);
        __syncthreads();
        *(uint4*)&As[srow][skof]      = a0;
        *(uint4*)&As[srow + 64][skof] = a1;
        *(uint4*)&Bs[srow][skof]      = b0;
        *(uint4*)&Bs[srow + 64][skof] = b1;
        __syncthreads();
        short8 af[4], bf[4];
        #pragma unroll
        for (int i = 0; i < 4; ++i) af[i] = *(const short8*)&As[wm + i * 16 + lrow][lk];
        #pragma unroll
        for (int j = 0; j < 4; ++j) bf[j] = *(const short8*)&Bs[wn + j * 16 + lrow][lk];
        #pragma unroll
        for (int i = 0; i < 4; ++i)
            #pragma unroll
            for (int j = 0; j < 4; ++j)
                acc[i][j] = __builtin_amdgcn_mfma_f32_16x16x32_bf16(af[i], bf[j], acc[i][j], 0, 0, 0);
    }
    const int crow0 = blockIdx.y * 128 + wm + (lane >> 4) * 4;
    const int ccol0 = blockIdx.x * 128 + wn + (lane & 15);
    #pragma unroll
    for (int j = 0; j < 4; ++j) {
        const float bv = bias ? bias[ccol0 + j * 16] : 0.f;
        #pragma unroll
        for (int i = 0; i < 4; ++i)
            #pragma unroll
            for (int rr = 0; rr < 4; ++rr)
                C[(size_t)(crow0 + i * 16 + rr) * N + (ccol0 + j * 16)] = acc[i][j][rr] + bv;
    }
}

// ---------------- encoder recurrence: 1024 thr/WG, K-split-2 GEMV ----------------
__global__ __launch_bounds__(1024) void encoder_rec(
    const float* __restrict__ gx,        // [B*S,1536]
    const _Float16* __restrict__ pUrz,   // [64][1024][8]
    const _Float16* __restrict__ pUn,    // [64][512][8]
    const float* __restrict__ brz, const float* __restrict__ bn,
    u16* __restrict__ enc_hs_bf,         // [B*S,512] bf16
    _Float16* __restrict__ spack,        // [B][16][512][8]
    float* __restrict__ h0dec, u32* __restrict__ h0p)
{
    const int b = blockIdx.x, tid = threadIdx.x;
    const int c = tid & 511, kh = tid >> 9;
    __shared__ __align__(16) u32 hp[256], rhp[256];
    __shared__ float hf[512], brzL[1024], bnL[512];
    __shared__ float redP[2048];   // [1024][2]
    __shared__ float redR[1024];   // [512][2]
    if (tid < 512) hf[tid] = 0.f;
    if (tid < 256) hp[tid] = 0u;
    brzL[tid] = brz[tid];
    if (tid < 512) bnL[tid] = bn[tid];
    __syncthreads();
    for (int t = 0; t < SEQ; ++t) {
        const float* gxr = gx + (size_t)(b * SEQ + t) * 1536;
        // P1 half-K partials for cols c (r) and 512+c (z)
        {
            float a0 = 0.f, a1 = 0.f;
            #pragma unroll 8
            for (int kb = kh * 32; kb < kh * 32 + 32; ++kb) {
                uint4 hv = *(const uint4*)&hp[kb * 4];
                uint4 w0 = *(const uint4*)(pUrz + ((size_t)kb * 1024 + c) * 8);
                uint4 w1 = *(const uint4*)(pUrz + ((size_t)kb * 1024 + 512 + c) * 8);
                dot4x(a0, w0, hv); dot4x(a1, w1, hv);
            }
            redP[c * 2 + kh] = a0;
            redP[(512 + c) * 2 + kh] = a1;
        }
        __syncthreads();
        float z = 0.f, hold = 0.f;
        if (tid < 512) {
            hold = hf[c];
            const float r = sigmoid_f(gxr[c] + redP[2 * c] + redP[2 * c + 1] + brzL[c]);
            z = sigmoid_f(gxr[512 + c] + redP[2 * (512 + c)] + redP[2 * (512 + c) + 1] + brzL[512 + c]);
            ((u16*)rhp)[c] = f2h_bits(r * hold);
        }
        __syncthreads();
        // P3: (r*h)@Un half-K partial
        {
            float un = 0.f;
            #pragma unroll 8
            for (int kb = kh * 32; kb < kh * 32 + 32; ++kb) {
                uint4 hv = *(const uint4*)&rhp[kb * 4];
                uint4 w = *(const uint4*)(pUn + ((size_t)kb * 512 + c) * 8);
                dot4x(un, w, hv);
            }
            redR[c * 2 + kh] = un;
        }
        __syncthreads();
        if (tid < 512) {
            const float n = tanh_f(gxr[1024 + c] + redR[2 * c] + redR[2 * c + 1] + bnL[c]);
            const float hnew = (1.f - z) * hold + z * n;
            hf[c] = hnew;
            ((u16*)hp)[c] = f2h_bits(hnew);
            enc_hs_bf[(size_t)(b * SEQ + t) * 512 + c] = f2bf(hnew);
            spack[(((size_t)b * 16 + (t >> 3)) * 512 + c) * 8 + (t & 7)] = (_Float16)hnew;
        }
        __syncthreads();
    }
    if (tid < 512) h0dec[b * 512 + tid] = hf[tid];
    if (tid < 256) h0p[b * 256 + tid] = hp[tid];
}

// ---------------- decoder recurrence: 1024 thr/WG, K-split-2 GEMV ----------------
__global__ __launch_bounds__(1024) void decoder_rec(
    const float* __restrict__ gxe,       // [B*T,1536]
    const u16* __restrict__ wh_bf,       // [B*S,512] bf16
    const _Float16* __restrict__ spack,  // [B][16][512][8]
    const _Float16* __restrict__ pWs,    // [64][512][8]
    const _Float16* __restrict__ pWxC,   // [64][1536][8]
    const _Float16* __restrict__ pUrz,   // [64][1024][8]
    const _Float16* __restrict__ pUn,    // [64][512][8]
    const float* __restrict__ attn_v,    // [512]
    const float* __restrict__ brz, const float* __restrict__ bn,
    const float* __restrict__ h0, const u32* __restrict__ h0pair,
    u16* __restrict__ hctx)              // [B*T,1024] bf16: [h | ctx]
{
    const int b = blockIdx.x, tid = threadIdx.x;
    const int c = tid & 511, kh = tid >> 9;
    __shared__ __align__(16) u32 hp[256], rhp[256], ctxp[256], attnp[64];
    __shared__ float hf[512];
    __shared__ float hWsP[544], avP[544];      // padded: elem e=g*64+i at g*68+i
    __shared__ float brzL[1024], bnL[512];
    __shared__ float redP[3072];   // [1536][2]  a0/a1/aw partials (persist to gates)
    __shared__ float redQ[3072];   // [1536][2]  gxc partials
    __shared__ float redE[1024];   // energy partials
    __shared__ float redC[1024];   // [512][2] ctx partials
    __shared__ float redR[1024];   // [512][2] un partials
    if (tid < 512) hf[tid] = h0[b * 512 + tid];
    if (tid < 256) hp[tid] = h0pair[b * 256 + tid];
    brzL[tid] = brz[tid];
    if (tid < 512) {
        bnL[tid] = bn[tid];
        avP[(tid >> 6) * 68 + (tid & 63)] = attn_v[tid];
    }
    __syncthreads();
    for (int t = 0; t < SEQ; ++t) {
        const float* gxr = gxe + (size_t)(b * SEQ + t) * 1536;
        // P1: h@[Urz|Ws] half-K partials
        {
            float a0 = 0.f, a1 = 0.f, aw = 0.f;
            #pragma unroll 8
            for (int kb = kh * 32; kb < kh * 32 + 32; ++kb) {
                uint4 hv = *(const uint4*)&hp[kb * 4];
                uint4 w0 = *(const uint4*)(pUrz + ((size_t)kb * 1024 + c) * 8);
                uint4 w1 = *(const uint4*)(pUrz + ((size_t)kb * 1024 + 512 + c) * 8);
                uint4 ww = *(const uint4*)(pWs + ((size_t)kb * 512 + c) * 8);
                dot4x(a0, w0, hv); dot4x(a1, w1, hv); dot4x(aw, ww, hv);
            }
            redP[c * 2 + kh] = a0;
            redP[(512 + c) * 2 + kh] = a1;
            redP[(1024 + c) * 2 + kh] = aw;
        }
        __syncthreads();
        if (tid < 512)
            hWsP[(c >> 6) * 68 + (c & 63)] = redP[(1024 + c) * 2] + redP[(1024 + c) * 2 + 1];
        __syncthreads();
        // P2: energy partials; thread -> (s = tid>>3, slice g = tid&7 of 64)
        {
            const int s = tid >> 3, g = tid & 7;
            const u16* whr = wh_bf + ((size_t)(b * SEQ + s) * 512 + g * 64);
            const float* hwp = &hWsP[g * 68];
            const float* vvp = &avP[g * 68];
            float e = 0.f;
            #pragma unroll
            for (int i = 0; i < 64; i += 8) {
                uint4 wv = *(const uint4*)(whr + i);
                float4 h0v = *(const float4*)(hwp + i);
                float4 h1v = *(const float4*)(hwp + i + 4);
                float4 v0 = *(const float4*)(vvp + i);
                float4 v1 = *(const float4*)(vvp + i + 4);
                e += v0.x * tanh_f(bf2f((u16)(wv.x & 0xFFFF)) + h0v.x)
                   + v0.y * tanh_f(bf2f((u16)(wv.x >> 16))   + h0v.y)
                   + v0.z * tanh_f(bf2f((u16)(wv.y & 0xFFFF)) + h0v.z)
                   + v0.w * tanh_f(bf2f((u16)(wv.y >> 16))   + h0v.w)
                   + v1.x * tanh_f(bf2f((u16)(wv.z & 0xFFFF)) + h1v.x)
                   + v1.y * tanh_f(bf2f((u16)(wv.z >> 16))   + h1v.y)
                   + v1.z * tanh_f(bf2f((u16)(wv.w & 0xFFFF)) + h1v.z)
                   + v1.w * tanh_f(bf2f((u16)(wv.w >> 16))   + h1v.w);
            }
            redE[tid] = e;
        }
        __syncthreads();
        // softmax over S=128 by wave 0
        if (tid < 64) {
            float e0 = 0.f, e1 = 0.f;
            #pragma unroll
            for (int j = 0; j < 8; ++j) {
                e0 += redE[tid * 8 + j];
                e1 += redE[(tid + 64) * 8 + j];
            }
            float m = fmaxf(e0, e1);
            for (int o = 32; o >= 1; o >>= 1) m = fmaxf(m, __shfl_xor(m, o));
            float p0 = fexp2((e0 - m) * 1.442695040888963f);
            float p1 = fexp2((e1 - m) * 1.442695040888963f);
            float ss = p0 + p1;
            for (int o = 32; o >= 1; o >>= 1) ss += __shfl_xor(ss, o);
            const float inv = frcp(ss);
            ((u16*)attnp)[tid]      = f2h_bits(p0 * inv);
            ((u16*)attnp)[tid + 64] = f2h_bits(p1 * inv);
        }
        __syncthreads();
        // ctx partials: half the s-blocks each
        {
            float cv = 0.f;
            const _Float16* sp = spack + (((size_t)b * 16 + kh * 8) * 512 + c) * 8;
            #pragma unroll
            for (int sb = 0; sb < 8; ++sb) {
                uint4 sv = *(const uint4*)(sp + (size_t)sb * 512 * 8);
                uint4 ap = *(const uint4*)&attnp[(kh * 8 + sb) * 4];
                dot4x(cv, sv, ap);
            }
            redC[c * 2 + kh] = cv;
        }
        __syncthreads();
        if (tid < 512) {
            const float cval = redC[2 * c] + redC[2 * c + 1];
            ((u16*)ctxp)[c] = f2h_bits(cval);
            hctx[(size_t)(b * SEQ + t) * 1024 + 512 + c] = f2bf(cval);
        }
        __syncthreads();
        // P3a: ctx@WxC half-K partials (3 outputs)
        {
            float g0 = 0.f, g1 = 0.f, g2 = 0.f;
            #pragma unroll 8
            for (int kb = kh * 32; kb < kh * 32 + 32; ++kb) {
                uint4 cv4 = *(const uint4*)&ctxp[kb * 4];
                uint4 w0 = *(const uint4*)(pWxC + ((size_t)kb * 1536 + c) * 8);
                uint4 w1 = *(const uint4*)(pWxC + ((size_t)kb * 1536 + 512 + c) * 8);
                uint4 w2 = *(const uint4*)(pWxC + ((size_t)kb * 1536 + 1024 + c) * 8);
                dot4x(g0, w0, cv4); dot4x(g1, w1, cv4); dot4x(g2, w2, cv4);
            }
            redQ[c * 2 + kh] = g0;
            redQ[(512 + c) * 2 + kh] = g1;
            redQ[(1024 + c) * 2 + kh] = g2;
        }
        __syncthreads();
        float z = 0.f, hold = 0.f;
        if (tid < 512) {
            hold = hf[c];
            const float r = sigmoid_f(gxr[c] + redQ[2 * c] + redQ[2 * c + 1]
                                      + redP[2 * c] + redP[2 * c + 1] + brzL[c]);
            z = sigmoid_f(gxr[512 + c] + redQ[2 * (512 + c)] + redQ[2 * (512 + c) + 1]
                          + redP[2 * (512 + c)] + redP[2 * (512 + c) + 1] + brzL[512 + c]);
            ((u16*)rhp)[c] = f2h_bits(r * hold);
        }
        __syncthreads();
        // P3b: (r*h)@Un half-K partial
        {
            float un = 0.f;
            #pragma unroll 8
            for (int kb = kh * 32; kb < kh * 32 + 32; ++kb) {
                uint4 hv = *(const uint4*)&rhp[kb * 4];
                uint4 w = *(const uint4*)(pUn + ((size_t)kb * 512 + c) * 8);
                dot4x(un, w, hv);
            }
            redR[c * 2 + kh] = un;
        }
        __syncthreads();
        if (tid < 512) {
            const float n = tanh_f(gxr[1024 + c] + redQ[2 * (1024 + c)] + redQ[2 * (1024 + c) + 1]
                                   + redR[2 * c] + redR[2 * c + 1] + bnL[c]);
            const float hnew = (1.f - z) * hold + z * n;
            hf[c] = hnew;
            ((u16*)hp)[c] = f2h_bits(hnew);
            hctx[(size_t)(b * SEQ + t) * 1024 + c] = f2bf(hnew);
        }
        __syncthreads();
    }
}

// ---------------- log_softmax per row, in-place on [4096, 32000] ----------------
__global__ __launch_bounds__(256) void log_softmax_rows(float* __restrict__ out)
{
    const int row = blockIdx.x, tid = threadIdx.x;
    float* p = out + (size_t)row * VTOK;
    __shared__ float rb[4];
    float m = -3.0e38f;
    for (int i = tid * 4; i < VTOK; i += 1024) {
        float4 v = *(const float4*)(p + i);
        m = fmaxf(m, fmaxf(fmaxf(v.x, v.y), fmaxf(v.z, v.w)));
    }
    for (int o = 32; o >= 1; o >>= 1) m = fmaxf(m, __shfl_xor(m, o));
    if ((tid & 63) == 0) rb[tid >> 6] = m;
    __syncthreads();
    m = fmaxf(fmaxf(rb[0], rb[1]), fmaxf(rb[2], rb[3]));
    float s = 0.f;
    for (int i = tid * 4; i < VTOK; i += 1024) {
        float4 v = *(const float4*)(p + i);
        s += fexp2((v.x - m) * 1.442695040888963f) + fexp2((v.y - m) * 1.442695040888963f)
           + fexp2((v.z - m) * 1.442695040888963f) + fexp2((v.w - m) * 1.442695040888963f);
    }
    for (int o = 32; o >= 1; o >>= 1) s += __shfl_xor(s, o);
    __syncthreads();
    if ((tid & 63) == 0) rb[tid >> 6] = s;
    __syncthreads();
    s = rb[0] + rb[1] + rb[2] + rb[3];
    const float lse = m + __builtin_amdgcn_logf(s) * 0.6931471805599453f;
    for (int i = tid * 4; i < VTOK; i += 1024) {
        float4 v = *(const float4*)(p + i);
        v.x -= lse; v.y -= lse; v.z -= lse; v.w -= lse;
        *(float4*)(p + i) = v;
    }
}

// ---------------- host launcher ----------------
extern "C" void kernel_launch(void* const* d_in, const int* in_sizes, int n_in,
                              void* d_out, int out_size, void* d_ws, size_t ws_size,
                              hipStream_t stream)
{
    (void)in_sizes; (void)n_in; (void)out_size; (void)ws_size;
    const int*   src       = (const int*)  d_in[0];
    const int*   tgt       = (const int*)  d_in[1];
    const float* enc_embed = (const float*)d_in[2];
    const float* enc_Wx    = (const float*)d_in[3];
    const float* enc_bx    = (const float*)d_in[4];
    const float* enc_Urz   = (const float*)d_in[5];
    const float* enc_brz   = (const float*)d_in[6];
    const float* enc_Un    = (const float*)d_in[7];
    const float* enc_bn    = (const float*)d_in[8];
    const float* dec_embed = (const float*)d_in[9];
    const float* dec_Wx    = (const float*)d_in[10];
    const float* dec_bx    = (const float*)d_in[11];
    const float* dec_Urz   = (const float*)d_in[12];
    const float* dec_brz   = (const float*)d_in[13];
    const float* dec_Un    = (const float*)d_in[14];
    const float* dec_bn    = (const float*)d_in[15];
    const float* attn_Wh   = (const float*)d_in[16];
    const float* attn_Ws   = (const float*)d_in[17];
    const float* attn_v    = (const float*)d_in[18];
    const float* out_W     = (const float*)d_in[19];
    const float* out_b     = (const float*)d_in[20];

    // --- scratch carved out of d_out (524,288,000 B); all consumed before the final GEMM ---
    char* ob = (char*)d_out;
    float*    gx_enc  = (float*)   (ob + 0);          // 25165824
    float*    gxe_dec = (float*)   (ob + 25165824);   // 25165824
    float*    wh_enc  = (float*)   (ob + 50331648);   // 8388608
    u16*      Aenc    = (u16*)     (ob + 58720256);   // 4194304
    u16*      Adec    = (u16*)     (ob + 62914560);   // 4194304
    u16*      enc_hs  = (u16*)     (ob + 67108864);   // 4194304
    _Float16* spack   = (_Float16*)(ob + 71303168);   // 4194304
    u16*      encWxT  = (u16*)     (ob + 75497472);   // 1572864
    u16*      WhT     = (u16*)     (ob + 77070336);   // 524288
    u16*      decWxET = (u16*)     (ob + 77594624);   // 1572864
    _Float16* pEncUrz = (_Float16*)(ob + 79167488);   // 1048576
    _Float16* pEncUn  = (_Float16*)(ob + 80216064);   // 524288
    _Float16* pDecUrz = (_Float16*)(ob + 80740352);   // 1048576
    _Float16* pDecUn  = (_Float16*)(ob + 81788928);   // 524288
    _Float16* pWs     = (_Float16*)(ob + 82313216);   // 524288
    _Float16* pWxC    = (_Float16*)(ob + 82837504);   // 1572864
    float*    h0dec   = (float*)   (ob + 84410368);   // 65536
    u32*      h0p     = (u32*)     (ob + 84475904);   // 32768
    u16*      wh_bf   = (u16*)     (ob + 84508672);   // 4194304

    // --- d_ws: only what must coexist with the final GEMM's output ---
    char* wb = (char*)d_ws;
    u16* outWT = (u16*)(wb + 0);          // 65536000
    u16* hctx  = (u16*)(wb + 65536000);   // 8388608

    transpose_cvt<<<dim3(48, 16),   256, 0, stream>>>(enc_Wx,  encWxT, 512, 1536);
    transpose_cvt<<<dim3(16, 16),   256, 0, stream>>>(attn_Wh, WhT,    512, 512);
    transpose_cvt<<<dim3(48, 16),   256, 0, stream>>>(dec_Wx,  decWxET,512, 1536);
    transpose_cvt<<<dim3(1000, 32), 256, 0, stream>>>(out_W,   outWT, 1024, 32000);
    pack8_f16<<<dim3(4, 64), 256, 0, stream>>>(enc_Urz, pEncUrz, 1024);
    pack8_f16<<<dim3(2, 64), 256, 0, stream>>>(enc_Un,  pEncUn,  512);
    pack8_f16<<<dim3(4, 64), 256, 0, stream>>>(dec_Urz, pDecUrz, 1024);
    pack8_f16<<<dim3(2, 64), 256, 0, stream>>>(dec_Un,  pDecUn,  512);
    pack8_f16<<<dim3(2, 64), 256, 0, stream>>>(attn_Ws, pWs,     512);
    pack8_f16<<<dim3(6, 64), 256, 0, stream>>>(dec_Wx + (size_t)512 * 1536, pWxC, 1536);
    gather_emb_bf16<<<4096, 128, 0, stream>>>(src, enc_embed, Aenc);
    gather_emb_bf16<<<4096, 128, 0, stream>>>(tgt, dec_embed, Adec);

    gemm_bf16<<<dim3(12, 32), 256, 0, stream>>>(Aenc, encWxT,  enc_bx, gx_enc,  4096, 1536, 512);
    gemm_bf16<<<dim3(12, 32), 256, 0, stream>>>(Adec, decWxET, dec_bx, gxe_dec, 4096, 1536, 512);

    encoder_rec<<<32, 1024, 0, stream>>>(gx_enc, pEncUrz, pEncUn, enc_brz, enc_bn,
                                         enc_hs, spack, h0dec, h0p);
    gemm_bf16<<<dim3(4, 32), 256, 0, stream>>>(enc_hs, WhT, nullptr, wh_enc, 4096, 512, 512);
    cvt_f32_bf16<<<1024, 256, 0, stream>>>(wh_enc, wh_bf);

    decoder_rec<<<32, 1024, 0, stream>>>(gxe_dec, wh_bf, spack, pWs, pWxC, pDecUrz, pDecUn,
                                         attn_v, dec_brz, dec_bn, h0dec, h0p, hctx);

    gemm_bf16<<<dim3(250, 32), 256, 0, stream>>>(hctx, outWT, out_b, (float*)d_out, 4096, VTOK, 1024);
    log_softmax_rows<<<4096, 256, 0, stream>>>((float*)d_out);
}